// Round 1
// baseline (66.394 us; speedup 1.0000x reference)
//
#include <hip/hip_runtime.h>

// MoEBudgetAwareINLLayer: 5 iterations of
//   error  = x - mu
//   v_next = ALPHA*v - BETA*error          (v_cand == 0)
//   x_next = x + GATE*v_next
// Elementwise over B=8192, D=2048 f32. Memory-bound: 3 reads + 2 writes
// = 320 MiB per call -> ~53 us floor at 6.3 TB/s.
//
// Inputs (setup_inputs order): d_in[0]=h (UNUSED by reference),
// d_in[1]=x_init, d_in[2]=v_init, d_in[3]=mu, d_in[4]=default_iterations (int).
// Output: tuple (x, v) concatenated flat: d_out[0:N]=x, d_out[N:2N]=v.

#define ALPHA 0.5f
#define BETA  0.1f
#define GATE  0.9f

__global__ __launch_bounds__(256) void inl_fused_kernel(
    const float4* __restrict__ x_init,
    const float4* __restrict__ v_init,
    const float4* __restrict__ mu,
    const int*    __restrict__ iters_p,
    float4* __restrict__ x_out,
    float4* __restrict__ v_out,
    int n_vec)
{
    const int iters = *iters_p;   // L1/L2-cached broadcast read, negligible
    const int stride = gridDim.x * blockDim.x;
    for (int i = blockIdx.x * blockDim.x + threadIdx.x; i < n_vec; i += stride) {
        float4 x4 = x_init[i];
        float4 v4 = v_init[i];
        float4 m4 = mu[i];
        float* x = reinterpret_cast<float*>(&x4);
        float* v = reinterpret_cast<float*>(&v4);
        float* m = reinterpret_cast<float*>(&m4);
        for (int t = 0; t < iters; ++t) {
            #pragma unroll
            for (int c = 0; c < 4; ++c) {
                float err = x[c] - m[c];
                v[c] = ALPHA * v[c] - BETA * err;
                x[c] = x[c] + GATE * v[c];
            }
        }
        x_out[i] = x4;
        v_out[i] = v4;
    }
}

extern "C" void kernel_launch(void* const* d_in, const int* in_sizes, int n_in,
                              void* d_out, int out_size, void* d_ws, size_t ws_size,
                              hipStream_t stream) {
    // d_in[0] = h (unused)
    const float* x_init = (const float*)d_in[1];
    const float* v_init = (const float*)d_in[2];
    const float* mu     = (const float*)d_in[3];
    const int*   iters  = (const int*)d_in[4];

    const int n = in_sizes[1];          // B*D = 16,777,216
    float* x_out = (float*)d_out;
    float* v_out = x_out + (size_t)n;

    const int n_vec = n / 4;            // N divisible by 4 (D=2048)
    const int block = 256;
    int grid = (n_vec + block - 1) / block;
    if (grid > 2048) grid = 2048;       // grid-stride the rest (G11)

    inl_fused_kernel<<<grid, block, 0, stream>>>(
        (const float4*)x_init, (const float4*)v_init, (const float4*)mu,
        iters, (float4*)x_out, (float4*)v_out, n_vec);
}

// Round 2
// 58.403 us; speedup vs baseline: 1.1368x; 1.1368x over previous
//
#include <hip/hip_runtime.h>

// MoEBudgetAwareINLLayer: 5 iterations of
//   error  = x - mu
//   v_next = ALPHA*v - BETA*error          (v_cand == 0)
//   x_next = x + GATE*v_next
// Elementwise over B=8192, D=2048 f32. Traffic: 3 reads + 2 writes = 320 MiB.
// R1 learning: grid-stride w/o unroll was latency-bound (VGPR=12, 3.5 TB/s HBM).
// Fix: 4x float4 batching per thread (12 loads in flight) + non-temporal
// stores so the 128 MiB write stream doesn't evict warm inputs from L3.
//
// Inputs: d_in[0]=h (UNUSED), d_in[1]=x_init, d_in[2]=v_init, d_in[3]=mu,
// d_in[4]=default_iterations. Output: (x, v) concat: d_out[0:N]=x, [N:2N]=v.

#define ALPHA 0.5f
#define BETA  0.1f
#define GATE  0.9f
#define UNROLL 4

typedef float v4f __attribute__((ext_vector_type(4)));

__global__ __launch_bounds__(256) void inl_fused_kernel(
    const float4* __restrict__ x_init,
    const float4* __restrict__ v_init,
    const float4* __restrict__ mu,
    const int*    __restrict__ iters_p,
    float4* __restrict__ x_out,
    float4* __restrict__ v_out,
    int n_vec)
{
    const int iters = *iters_p;
    const int T = gridDim.x * blockDim.x;          // total threads
    int i = blockIdx.x * blockDim.x + threadIdx.x;

    // Main path: UNROLL float4s per thread, coalesced (lane-contiguous per k).
    for (; i + (UNROLL - 1) * T < n_vec; i += UNROLL * T) {
        float4 x4[UNROLL], v4[UNROLL], m4[UNROLL];
        #pragma unroll
        for (int k = 0; k < UNROLL; ++k) x4[k] = x_init[i + k * T];
        #pragma unroll
        for (int k = 0; k < UNROLL; ++k) v4[k] = v_init[i + k * T];
        #pragma unroll
        for (int k = 0; k < UNROLL; ++k) m4[k] = mu[i + k * T];

        for (int t = 0; t < iters; ++t) {
            #pragma unroll
            for (int k = 0; k < UNROLL; ++k) {
                float* x = reinterpret_cast<float*>(&x4[k]);
                float* v = reinterpret_cast<float*>(&v4[k]);
                float* m = reinterpret_cast<float*>(&m4[k]);
                #pragma unroll
                for (int c = 0; c < 4; ++c) {
                    float err = x[c] - m[c];
                    v[c] = ALPHA * v[c] - BETA * err;
                    x[c] = x[c] + GATE * v[c];
                }
            }
        }

        #pragma unroll
        for (int k = 0; k < UNROLL; ++k)
            __builtin_nontemporal_store(*(const v4f*)&x4[k], (v4f*)&x_out[i + k * T]);
        #pragma unroll
        for (int k = 0; k < UNROLL; ++k)
            __builtin_nontemporal_store(*(const v4f*)&v4[k], (v4f*)&v_out[i + k * T]);
    }

    // Tail (not taken for N=16.7M with exact grid, kept for generality).
    for (; i < n_vec; i += T) {
        float4 x4 = x_init[i];
        float4 v4 = v_init[i];
        float4 m4 = mu[i];
        float* x = reinterpret_cast<float*>(&x4);
        float* v = reinterpret_cast<float*>(&v4);
        float* m = reinterpret_cast<float*>(&m4);
        for (int t = 0; t < iters; ++t) {
            #pragma unroll
            for (int c = 0; c < 4; ++c) {
                float err = x[c] - m[c];
                v[c] = ALPHA * v[c] - BETA * err;
                x[c] = x[c] + GATE * v[c];
            }
        }
        __builtin_nontemporal_store(*(const v4f*)&x4, (v4f*)&x_out[i]);
        __builtin_nontemporal_store(*(const v4f*)&v4, (v4f*)&v_out[i]);
    }
}

extern "C" void kernel_launch(void* const* d_in, const int* in_sizes, int n_in,
                              void* d_out, int out_size, void* d_ws, size_t ws_size,
                              hipStream_t stream) {
    // d_in[0] = h (unused by reference)
    const float* x_init = (const float*)d_in[1];
    const float* v_init = (const float*)d_in[2];
    const float* mu     = (const float*)d_in[3];
    const int*   iters  = (const int*)d_in[4];

    const int n = in_sizes[1];          // B*D = 16,777,216
    float* x_out = (float*)d_out;
    float* v_out = x_out + (size_t)n;

    const int n_vec = n / 4;            // 4,194,304 float4s
    const int block = 256;
    int grid = (n_vec + block * UNROLL - 1) / (block * UNROLL);  // 4096: exact
    if (grid > 8192) grid = 8192;

    inl_fused_kernel<<<grid, block, 0, stream>>>(
        (const float4*)x_init, (const float4*)v_init, (const float4*)mu,
        iters, (float4*)x_out, (float4*)v_out, n_vec);
}